// Round 1
// baseline (7010.957 us; speedup 1.0000x reference)
//
#include <hip/hip_runtime.h>
#include <hip/hip_bf16.h>
#include <math.h>

// Problem constants
#define GG 33538
#define DD 256
#define OO 512
#define LL 6
#define HH 8
#define KK 2048
#define BB 4
#define TT 2049          // K+1 tokens
#define FF2 1024         // 4*D
#define BT (BB*TT)       // 8196

__device__ __forceinline__ float gelu_f(float x) {
    return 0.5f * x * (1.0f + erff(x * 0.70710678118654752440f));
}

__device__ __forceinline__ unsigned to_key(float x) {
    unsigned u = __float_as_uint(x);
    return (u & 0x80000000u) ? ~u : (u | 0x80000000u);
}

// ---------------- Top-K (radix select, exact tie handling) ----------------
// one block of 1024 threads per batch row
__device__ int block_scan_excl_1024(int v, int* shw) {
    int lane = threadIdx.x & 63, w = threadIdx.x >> 6;
    int x = v;
    #pragma unroll
    for (int o = 1; o < 64; o <<= 1) {
        int t = __shfl_up(x, o, 64);
        if (lane >= o) x += t;
    }
    if (lane == 63) shw[w] = x;
    __syncthreads();
    if (w == 0) {
        int y = (lane < 16) ? shw[lane] : 0;
        #pragma unroll
        for (int o = 1; o < 16; o <<= 1) {
            int t = __shfl_up(y, o, 64);
            if (lane >= o) y += t;
        }
        if (lane < 16) shw[lane] = y;
    }
    __syncthreads();
    int off = (w == 0) ? 0 : shw[w - 1];
    int res = off + x - v;   // exclusive prefix
    return res;
}

__global__ __launch_bounds__(1024) void topk_kernel(const float* __restrict__ expr,
                                                    int* __restrict__ idxout,
                                                    int* __restrict__ cntout) {
    __shared__ unsigned hist[256];
    __shared__ int shw[16];
    __shared__ unsigned sh_prefix;
    __shared__ int sh_want;
    __shared__ int sh_tot;

    int b = blockIdx.x;
    int tid = threadIdx.x;
    const float* row = expr + (size_t)b * GG;

    unsigned prefix = 0;
    int want = KK;
    for (int p = 3; p >= 0; --p) {
        for (int i = tid; i < 256; i += 1024) hist[i] = 0u;
        __syncthreads();
        int shift = p * 8;
        unsigned pmask = (p == 3) ? 0u : (0xFFFFFFFFu << (shift + 8));
        for (int g = tid; g < GG; g += 1024) {
            unsigned key = to_key(row[g]);
            if ((key & pmask) == (prefix & pmask))
                atomicAdd(&hist[(key >> shift) & 255u], 1u);
        }
        __syncthreads();
        if (tid == 0) {
            int cum = 0, bin = 0;
            for (int i = 255; i >= 0; --i) {
                int c = (int)hist[i];
                if (cum + c >= want) { bin = i; break; }
                cum += c;
            }
            sh_prefix = prefix | ((unsigned)bin << shift);
            sh_want = want - cum;
        }
        __syncthreads();
        prefix = sh_prefix;
        want = sh_want;
        __syncthreads();
    }
    unsigned kth = prefix;

    // ordered pass: ascending-index output of active = (selected && expr>0)
    int base_eq = 0, base_out = 0;
    for (int g0 = 0; g0 < GG; g0 += 1024) {
        int g = g0 + tid;
        bool in = (g < GG);
        float e = in ? row[g] : -1.0f;
        unsigned key = in ? to_key(e) : 0u;
        int is_eq = (in && key == kth) ? 1 : 0;

        int eqr = block_scan_excl_1024(is_eq, shw);
        if (tid == 1023) sh_tot = eqr + is_eq;
        __syncthreads();
        int eq_tot = sh_tot;
        int eq_rank = base_eq + eqr;
        base_eq += eq_tot;
        __syncthreads();

        int selected = ((in && key > kth) || (is_eq && eq_rank < want)) ? 1 : 0;
        int act = (selected && e > 0.0f) ? 1 : 0;

        int pos = block_scan_excl_1024(act, shw);
        if (tid == 1023) sh_tot = pos + act;
        __syncthreads();
        int act_tot = sh_tot;
        if (act) idxout[b * KK + base_out + pos] = g;
        base_out += act_tot;
        __syncthreads();
    }
    if (tid == 0) cntout[b] = base_out;
}

// ---------------- Token embedding ----------------
__global__ __launch_bounds__(256) void build_h_kernel(const float* __restrict__ expr,
                                                      const int* __restrict__ idxb,
                                                      const int* __restrict__ cntb,
                                                      const float* __restrict__ ep_w1,
                                                      const float* __restrict__ ep_b1,
                                                      float* __restrict__ H) {
    int i = blockIdx.x * 256 + threadIdx.x;       // < BB*KK*DD
    int r = i >> 8, d = i & 255;
    int b = r >> 11, jj = r & (KK - 1);
    float v = 0.0f;
    if (jj < cntb[b]) {
        int g = idxb[b * KK + jj];
        float e = expr[(size_t)b * GG + g];
        v = gelu_f(e * ep_w1[d] + ep_b1[d]);
    }
    H[i] = v;
}

__global__ __launch_bounds__(256) void assemble_kernel(const float* __restrict__ VAL,
                                                       const float* __restrict__ gene_emb,
                                                       const float* __restrict__ clsv,
                                                       const int* __restrict__ idxb,
                                                       const int* __restrict__ cntb,
                                                       float* __restrict__ x) {
    int i = blockIdx.x * 256 + threadIdx.x;       // < BT*DD
    int r = i >> 8, d = i & 255;
    int b = r / TT, t = r % TT;
    float v;
    if (t == 0) {
        v = clsv[d];
    } else {
        int jj = t - 1;
        if (jj < cntb[b]) {
            int g = idxb[b * KK + jj];
            v = gene_emb[(size_t)g * DD + d] + VAL[((size_t)b * KK + jj) * DD + d];
        } else {
            v = 0.0f;
        }
    }
    x[i] = v;
}

// ---------------- LayerNorm (row of 256) ----------------
__device__ __forceinline__ float blocksum256(float v, float* sh) {
    #pragma unroll
    for (int o = 1; o < 64; o <<= 1) v += __shfl_xor(v, o, 64);
    int w = threadIdx.x >> 6;
    if ((threadIdx.x & 63) == 0) sh[w] = v;
    __syncthreads();
    float t = sh[0] + sh[1] + sh[2] + sh[3];
    __syncthreads();
    return t;
}

__global__ __launch_bounds__(256) void ln_kernel(const float* __restrict__ X,
                                                 const float* __restrict__ s,
                                                 const float* __restrict__ bsh,
                                                 float* __restrict__ Y) {
    __shared__ float sh[4];
    size_t r = blockIdx.x;
    float x = X[r * DD + threadIdx.x];
    float mu = blocksum256(x, sh) * (1.0f / 256.0f);
    float d = x - mu;
    float var = blocksum256(d * d, sh) * (1.0f / 256.0f);
    float y = d * rsqrtf(var + 1e-5f) * s[threadIdx.x] + bsh[threadIdx.x];
    Y[r * DD + threadIdx.x] = y;
}

// ---------------- generic GEMM: C = act(A @ W^T + bias) (+R) ----------------
// A: M x K (row-major), W: N x K (row-major), C: M x N
__global__ __launch_bounds__(256) void gemm_nt(const float* __restrict__ A,
                                               const float* __restrict__ W,
                                               const float* __restrict__ bias,
                                               const float* __restrict__ R,
                                               float* __restrict__ C,
                                               int M, int N, int K, int act) {
    __shared__ float As[16][68];
    __shared__ float Ws[16][68];
    int tid = threadIdx.x;
    int tx = tid & 15, ty = tid >> 4;
    int bm = blockIdx.y * 64, bn = blockIdx.x * 64;
    float c[4][4] = {{0.f}};

    for (int k0 = 0; k0 < K; k0 += 16) {
        #pragma unroll
        for (int i = 0; i < 4; ++i) {
            int idx = tid + i * 256;          // 0..1023
            int m = idx >> 4, kk = idx & 15;
            int gm = bm + m;
            As[kk][m] = (gm < M) ? A[(size_t)gm * K + k0 + kk] : 0.0f;
            int gn = bn + m;
            Ws[kk][m] = (gn < N) ? W[(size_t)gn * K + k0 + kk] : 0.0f;
        }
        __syncthreads();
        #pragma unroll
        for (int kk = 0; kk < 16; ++kk) {
            float4 a4 = *(const float4*)&As[kk][ty * 4];
            float4 b4 = *(const float4*)&Ws[kk][tx * 4];
            float av[4] = {a4.x, a4.y, a4.z, a4.w};
            float bv[4] = {b4.x, b4.y, b4.z, b4.w};
            #pragma unroll
            for (int i = 0; i < 4; ++i)
                #pragma unroll
                for (int j = 0; j < 4; ++j)
                    c[i][j] += av[i] * bv[j];
        }
        __syncthreads();
    }

    #pragma unroll
    for (int i = 0; i < 4; ++i) {
        int gm = bm + ty * 4 + i;
        if (gm >= M) continue;
        #pragma unroll
        for (int j = 0; j < 4; ++j) {
            int gn = bn + tx * 4 + j;
            if (gn >= N) continue;
            float v = c[i][j] + bias[gn];
            if (R) v += R[(size_t)gm * N + gn];
            if (act == 1) v = gelu_f(v);
            C[(size_t)gm * N + gn] = v;
        }
    }
}

// ---------------- attention (streaming online softmax) ----------------
#define CH 128
__global__ __launch_bounds__(256) void attn_kernel(const float* __restrict__ qkv,
                                                   const int* __restrict__ cnt,
                                                   float* __restrict__ attno) {
    __shared__ float kls[CH][32];
    __shared__ float vls[CH][32];
    int bh = blockIdx.x;
    int b = bh >> 3, h = bh & 7;
    int t = blockIdx.y * 256 + threadIdx.x;
    int nvalid = cnt[b] + 1;
    const float rscale = 0.17677669529663688f;   // 1/sqrt(32)

    float q[32];
    bool live = (t < TT);
    if (live) {
        const float* qp = qkv + ((size_t)(b * TT + t)) * 768 + h * 32;
        #pragma unroll
        for (int d = 0; d < 32; ++d) q[d] = qp[d];
    }
    float m = -1e30f, l = 0.0f, o[32];
    #pragma unroll
    for (int d = 0; d < 32; ++d) o[d] = 0.0f;

    for (int k0 = 0; k0 < nvalid; k0 += CH) {
        int nk = min(CH, nvalid - k0);
        __syncthreads();
        for (int i2 = threadIdx.x; i2 < CH * 32; i2 += 256) {
            int row = i2 >> 5, d = i2 & 31;
            if (row < nk) {
                const float* kp = qkv + ((size_t)(b * TT + k0 + row)) * 768 + 256 + h * 32;
                kls[row][d] = kp[d];
                vls[row][d] = kp[256 + d];
            }
        }
        __syncthreads();
        if (live) {
            for (int i2 = 0; i2 < nk; ++i2) {
                float s = 0.0f;
                #pragma unroll
                for (int d = 0; d < 32; ++d) s += q[d] * kls[i2][d];
                s *= rscale;
                if (s > m) {
                    float corr = expf(m - s);
                    l = l * corr + 1.0f;
                    #pragma unroll
                    for (int d = 0; d < 32; ++d) o[d] = o[d] * corr + vls[i2][d];
                    m = s;
                } else {
                    float p = expf(s - m);
                    l += p;
                    #pragma unroll
                    for (int d = 0; d < 32; ++d) o[d] += p * vls[i2][d];
                }
            }
        }
    }
    if (live) {
        float rl = 1.0f / l;
        float* op = attno + ((size_t)(b * TT + t)) * DD + h * 32;
        #pragma unroll
        for (int d = 0; d < 32; ++d) op[d] = o[d] * rl;
    }
}

// ---------------- head ----------------
__global__ __launch_bounds__(512) void head_kernel(const float* __restrict__ Y,
                                                   const float* __restrict__ w1,
                                                   const float* __restrict__ b1,
                                                   const float* __restrict__ w2,
                                                   const float* __restrict__ b2,
                                                   float* __restrict__ out) {
    __shared__ float clsr[256];
    __shared__ float t1[512];
    int b = blockIdx.x, tid = threadIdx.x;
    if (tid < 256) clsr[tid] = Y[((size_t)b * TT) * DD + tid];
    __syncthreads();
    float acc = b1[tid];
    const float* w = w1 + (size_t)tid * 256;
    for (int k = 0; k < 256; ++k) acc += clsr[k] * w[k];
    t1[tid] = gelu_f(acc);
    __syncthreads();
    float acc2 = b2[tid];
    const float* wr = w2 + (size_t)tid * 512;
    for (int k = 0; k < 512; ++k) acc2 += t1[k] * wr[k];
    out[(size_t)b * 512 + tid] = acc2;
}

// ---------------- launch ----------------
extern "C" void kernel_launch(void* const* d_in, const int* in_sizes, int n_in,
                              void* d_out, int out_size, void* d_ws, size_t ws_size,
                              hipStream_t stream) {
    (void)in_sizes; (void)n_in; (void)out_size; (void)ws_size;
    const float* expr     = (const float*)d_in[0];
    const float* gene_emb = (const float*)d_in[1];
    const float* ep_w1    = (const float*)d_in[2];
    const float* ep_b1    = (const float*)d_in[3];
    const float* ep_w2    = (const float*)d_in[4];
    const float* ep_b2    = (const float*)d_in[5];
    const float* clsv     = (const float*)d_in[6];
    const float* ln1_s    = (const float*)d_in[7];
    const float* ln1_b    = (const float*)d_in[8];
    const float* qkv_w    = (const float*)d_in[9];
    const float* qkv_b    = (const float*)d_in[10];
    const float* out_w    = (const float*)d_in[11];
    const float* out_b    = (const float*)d_in[12];
    const float* ln2_s    = (const float*)d_in[13];
    const float* ln2_b    = (const float*)d_in[14];
    const float* ff_w1    = (const float*)d_in[15];
    const float* ff_b1    = (const float*)d_in[16];
    const float* ff_w2    = (const float*)d_in[17];
    const float* ff_b2    = (const float*)d_in[18];
    const float* fn_s     = (const float*)d_in[19];
    const float* fn_b     = (const float*)d_in[20];
    const float* pr_w1    = (const float*)d_in[21];
    const float* pr_b1    = (const float*)d_in[22];
    const float* pr_w2    = (const float*)d_in[23];
    const float* pr_b2    = (const float*)d_in[24];
    float* outp = (float*)d_out;

    const size_t XSZ = (size_t)BT * DD;        // 2,098,176
    const size_t QSZ = (size_t)BT * 768;       // 6,294,528
    const size_t FSZ = (size_t)BT * FF2;       // 8,392,704

    float* ws0   = (float*)d_ws;
    float* x     = ws0;
    float* y     = x + XSZ;
    float* attno = y + XSZ;
    float* qkvb  = attno + XSZ;
    float* ff1   = qkvb + QSZ;
    int*   idxb  = (int*)(ff1 + FSZ);
    int*   cntb  = idxb + BB * KK;
    float* H     = ff1;     // reused before FF buffer is needed
    float* VAL   = qkvb;    // reused before QKV buffer is needed

    // 1) top-K selection
    topk_kernel<<<BB, 1024, 0, stream>>>(expr, idxb, cntb);

    // 2) token embeddings for selected genes
    build_h_kernel<<<(BB * KK * DD) / 256, 256, 0, stream>>>(expr, idxb, cntb, ep_w1, ep_b1, H);
    gemm_nt<<<dim3(DD / 64, (BB * KK) / 64), 256, 0, stream>>>(H, ep_w2, ep_b2, nullptr, VAL,
                                                               BB * KK, DD, DD, 0);
    assemble_kernel<<<(BT * DD) / 256, 256, 0, stream>>>(VAL, gene_emb, clsv, idxb, cntb, x);

    // 3) transformer layers
    int mg = (BT + 63) / 64;   // 129
    for (int i = 0; i < LL; ++i) {
        ln_kernel<<<BT, 256, 0, stream>>>(x, ln1_s + i * DD, ln1_b + i * DD, y);
        gemm_nt<<<dim3(768 / 64, mg), 256, 0, stream>>>(y, qkv_w + (size_t)i * 768 * DD,
                                                        qkv_b + i * 768, nullptr, qkvb,
                                                        BT, 768, DD, 0);
        attn_kernel<<<dim3(BB * HH, (TT + 255) / 256), 256, 0, stream>>>(qkvb, cntb, attno);
        gemm_nt<<<dim3(DD / 64, mg), 256, 0, stream>>>(attno, out_w + (size_t)i * DD * DD,
                                                       out_b + i * DD, x, x,
                                                       BT, DD, DD, 0);
        ln_kernel<<<BT, 256, 0, stream>>>(x, ln2_s + i * DD, ln2_b + i * DD, y);
        gemm_nt<<<dim3(FF2 / 64, mg), 256, 0, stream>>>(y, ff_w1 + (size_t)i * FF2 * DD,
                                                        ff_b1 + i * FF2, nullptr, ff1,
                                                        BT, FF2, DD, 1);
        gemm_nt<<<dim3(DD / 64, mg), 256, 0, stream>>>(ff1, ff_w2 + (size_t)i * DD * FF2,
                                                       ff_b2 + i * DD, x, x,
                                                       BT, DD, FF2, 0);
    }

    // 4) final LN + head (only CLS rows matter, LN over all rows is cheap)
    ln_kernel<<<BT, 256, 0, stream>>>(x, fn_s, fn_b, y);
    head_kernel<<<BB, 512, 0, stream>>>(y, pr_w1, pr_b1, pr_w2, pr_b2, outp);
}

// Round 3
// 1377.741 us; speedup vs baseline: 5.0887x; 5.0887x over previous
//
#include <hip/hip_runtime.h>
#include <hip/hip_bf16.h>
#include <math.h>

// Problem constants
#define GG 33538
#define DD 256
#define LL 6
#define HH 8
#define KK 2048
#define BB 4
#define TT 2049          // K+1 tokens
#define BT (BB*TT)       // 8196

typedef __bf16 bf16x8 __attribute__((ext_vector_type(8)));
typedef float f32x4 __attribute__((ext_vector_type(4)));
typedef float f32x16 __attribute__((ext_vector_type(16)));
typedef unsigned short ub16;

union BW { __bf16 h; ub16 u; };
__device__ __forceinline__ ub16 f2b(float x) { BW w; w.h = (__bf16)x; return w.u; }
__device__ __forceinline__ unsigned pk2(float a, float b) {
    return (unsigned)f2b(a) | ((unsigned)f2b(b) << 16);
}
union U4B { unsigned u[4]; bf16x8 v; };

__device__ __forceinline__ float gelu_f(float x) {
    return 0.5f * x * (1.0f + erff(x * 0.70710678118654752440f));
}

__device__ __forceinline__ unsigned to_key(float x) {
    unsigned u = __float_as_uint(x);
    return (u & 0x80000000u) ? ~u : (u | 0x80000000u);
}

// ---------------- Top-K (radix select, exact tie handling) ----------------
__device__ int block_scan_excl_1024(int v, int* shw) {
    int lane = threadIdx.x & 63, w = threadIdx.x >> 6;
    int x = v;
    #pragma unroll
    for (int o = 1; o < 64; o <<= 1) {
        int t = __shfl_up(x, o, 64);
        if (lane >= o) x += t;
    }
    if (lane == 63) shw[w] = x;
    __syncthreads();
    if (w == 0) {
        int y = (lane < 16) ? shw[lane] : 0;
        #pragma unroll
        for (int o = 1; o < 16; o <<= 1) {
            int t = __shfl_up(y, o, 64);
            if (lane >= o) y += t;
        }
        if (lane < 16) shw[lane] = y;
    }
    __syncthreads();
    int off = (w == 0) ? 0 : shw[w - 1];
    return off + x - v;   // exclusive prefix
}

__global__ __launch_bounds__(1024) void topk_kernel(const float* __restrict__ expr,
                                                    int* __restrict__ idxout,
                                                    int* __restrict__ cntout) {
    __shared__ unsigned hist[256];
    __shared__ int shw[16];
    __shared__ unsigned sh_prefix;
    __shared__ int sh_want;
    __shared__ int sh_tot;

    int b = blockIdx.x;
    int tid = threadIdx.x;
    const float* row = expr + (size_t)b * GG;

    unsigned prefix = 0;
    int want = KK;
    for (int p = 3; p >= 0; --p) {
        for (int i = tid; i < 256; i += 1024) hist[i] = 0u;
        __syncthreads();
        int shift = p * 8;
        unsigned pmask = (p == 3) ? 0u : (0xFFFFFFFFu << (shift + 8));
        for (int g = tid; g < GG; g += 1024) {
            unsigned key = to_key(row[g]);
            if ((key & pmask) == (prefix & pmask))
                atomicAdd(&hist[(key >> shift) & 255u], 1u);
        }
        __syncthreads();
        if (tid == 0) {
            int cum = 0, bin = 0;
            for (int i = 255; i >= 0; --i) {
                int c = (int)hist[i];
                if (cum + c >= want) { bin = i; break; }
                cum += c;
            }
            sh_prefix = prefix | ((unsigned)bin << shift);
            sh_want = want - cum;
        }
        __syncthreads();
        prefix = sh_prefix;
        want = sh_want;
        __syncthreads();
    }
    unsigned kth = prefix;

    int base_eq = 0, base_out = 0;
    for (int g0 = 0; g0 < GG; g0 += 1024) {
        int g = g0 + tid;
        bool in = (g < GG);
        float e = in ? row[g] : -1.0f;
        unsigned key = in ? to_key(e) : 0u;
        int is_eq = (in && key == kth) ? 1 : 0;

        int eqr = block_scan_excl_1024(is_eq, shw);
        if (tid == 1023) sh_tot = eqr + is_eq;
        __syncthreads();
        int eq_tot = sh_tot;
        int eq_rank = base_eq + eqr;
        base_eq += eq_tot;
        __syncthreads();

        int selected = ((in && key > kth) || (is_eq && eq_rank < want)) ? 1 : 0;
        int act = (selected && e > 0.0f) ? 1 : 0;

        int pos = block_scan_excl_1024(act, shw);
        if (tid == 1023) sh_tot = pos + act;
        __syncthreads();
        int act_tot = sh_tot;
        if (act) idxout[b * KK + base_out + pos] = g;
        base_out += act_tot;
        __syncthreads();
    }
    if (tid == 0) cntout[b] = base_out;
}

// ---------------- weight fp32 -> bf16 ----------------
__global__ __launch_bounds__(256) void cvt_bf16_kernel(const float* __restrict__ s,
                                                       ub16* __restrict__ d, int n) {
    int i = blockIdx.x * 256 + threadIdx.x;
    if (i < n) d[i] = f2b(s[i]);
}

// ---------------- Token embedding ----------------
__global__ __launch_bounds__(256) void build_h_kernel(const float* __restrict__ expr,
                                                      const int* __restrict__ idxb,
                                                      const int* __restrict__ cntb,
                                                      const float* __restrict__ ep_w1,
                                                      const float* __restrict__ ep_b1,
                                                      ub16* __restrict__ H) {
    int i = blockIdx.x * 256 + threadIdx.x;       // < BB*KK*DD
    int r = i >> 8, d = i & 255;
    int b = r >> 11, jj = r & (KK - 1);
    float v = 0.0f;
    if (jj < cntb[b]) {
        int g = idxb[b * KK + jj];
        float e = expr[(size_t)b * GG + g];
        v = gelu_f(e * ep_w1[d] + ep_b1[d]);
    }
    H[i] = f2b(v);
}

__global__ __launch_bounds__(256) void assemble_kernel(const float* __restrict__ VAL,
                                                       const float* __restrict__ gene_emb,
                                                       const float* __restrict__ clsv,
                                                       const int* __restrict__ idxb,
                                                       const int* __restrict__ cntb,
                                                       float* __restrict__ x) {
    int i = blockIdx.x * 256 + threadIdx.x;       // < BT*DD
    int r = i >> 8, d = i & 255;
    int b = r / TT, t = r % TT;
    float v;
    if (t == 0) {
        v = clsv[d];
    } else {
        int jj = t - 1;
        if (jj < cntb[b]) {
            int g = idxb[b * KK + jj];
            v = gene_emb[(size_t)g * DD + d] + VAL[((size_t)b * KK + jj) * DD + d];
        } else {
            v = 0.0f;
        }
    }
    x[i] = v;
}

// ---------------- LayerNorm ----------------
__device__ __forceinline__ float blocksum256(float v, float* sh) {
    #pragma unroll
    for (int o = 1; o < 64; o <<= 1) v += __shfl_xor(v, o, 64);
    int w = threadIdx.x >> 6;
    if ((threadIdx.x & 63) == 0) sh[w] = v;
    __syncthreads();
    float t = sh[0] + sh[1] + sh[2] + sh[3];
    __syncthreads();
    return t;
}

__global__ __launch_bounds__(256) void ln_kernel(const float* __restrict__ X,
                                                 const float* __restrict__ s,
                                                 const float* __restrict__ bsh,
                                                 ub16* __restrict__ Y16,
                                                 float* __restrict__ Yf) {
    __shared__ float sh[4];
    size_t r = blockIdx.x;
    float x = X[r * DD + threadIdx.x];
    float mu = blocksum256(x, sh) * (1.0f / 256.0f);
    float d = x - mu;
    float var = blocksum256(d * d, sh) * (1.0f / 256.0f);
    float y = d * rsqrtf(var + 1e-5f) * s[threadIdx.x] + bsh[threadIdx.x];
    if (Y16) Y16[r * DD + threadIdx.x] = f2b(y);
    else     Yf[r * DD + threadIdx.x] = y;
}

// ---------------- bf16 MFMA NT-GEMM: C = act(A @ W^T + bias) (+R) ----------------
// A: M x K bf16, W: N x K bf16. Tile 64x64, BK=32, 4 waves (2x2 quadrants).
__global__ __launch_bounds__(256) void gemm_bt16(const ub16* __restrict__ A,
                                                 const ub16* __restrict__ W,
                                                 const float* __restrict__ bias,
                                                 const float* __restrict__ R,
                                                 float* __restrict__ Cf,
                                                 ub16* __restrict__ Ch,
                                                 int M, int N, int K, int gelu_flag) {
    __shared__ ub16 As[64][40];
    __shared__ ub16 Ws[64][40];
    int tid = threadIdx.x;
    int lane = tid & 63, w = tid >> 6;
    int wr = (w >> 1) * 32, wc = (w & 1) * 32;
    int bm = blockIdx.y * 64, bn = blockIdx.x * 64;
    f32x4 acc[2][2] = {};

    int lrow = tid >> 2, lc8 = (tid & 3) * 8;
    int arow = min(bm + lrow, M - 1);
    const ub16* ap = A + (size_t)arow * K + lc8;
    const ub16* wp = W + (size_t)(bn + lrow) * K + lc8;

    int fr = lane & 15, fc = 8 * (lane >> 4);
    for (int k0 = 0; k0 < K; k0 += 32) {
        bf16x8 av = *(const bf16x8*)(ap + k0);
        bf16x8 wv = *(const bf16x8*)(wp + k0);
        *(bf16x8*)&As[lrow][lc8] = av;
        *(bf16x8*)&Ws[lrow][lc8] = wv;
        __syncthreads();
        bf16x8 a0 = *(const bf16x8*)&As[wr + fr][fc];
        bf16x8 a1 = *(const bf16x8*)&As[wr + 16 + fr][fc];
        bf16x8 b0 = *(const bf16x8*)&Ws[wc + fr][fc];
        bf16x8 b1 = *(const bf16x8*)&Ws[wc + 16 + fr][fc];
        acc[0][0] = __builtin_amdgcn_mfma_f32_16x16x32_bf16(a0, b0, acc[0][0], 0, 0, 0);
        acc[0][1] = __builtin_amdgcn_mfma_f32_16x16x32_bf16(a0, b1, acc[0][1], 0, 0, 0);
        acc[1][0] = __builtin_amdgcn_mfma_f32_16x16x32_bf16(a1, b0, acc[1][0], 0, 0, 0);
        acc[1][1] = __builtin_amdgcn_mfma_f32_16x16x32_bf16(a1, b1, acc[1][1], 0, 0, 0);
        __syncthreads();
    }

    #pragma unroll
    for (int i = 0; i < 2; ++i) {
        #pragma unroll
        for (int j = 0; j < 2; ++j) {
            #pragma unroll
            for (int reg = 0; reg < 4; ++reg) {
                int gm = bm + wr + i * 16 + (lane >> 4) * 4 + reg;
                int gn = bn + wc + j * 16 + (lane & 15);
                if (gm >= M) continue;
                float v = acc[i][j][reg] + bias[gn];
                if (R) v += R[(size_t)gm * N + gn];
                if (gelu_flag) v = gelu_f(v);
                if (Cf) Cf[(size_t)gm * N + gn] = v;
                else    Ch[(size_t)gm * N + gn] = f2b(v);
            }
        }
    }
}

// ---------------- MFMA flash attention ----------------
// grid (B*H, 17); block 256 = 4 waves; wave = one 32-query tile.
// S^T = mfma(K_frag, Q_frag) so query = lane&31 (stats lane-local).
__global__ __launch_bounds__(256) void attn_mfma(const ub16* __restrict__ qkv,
                                                 const int* __restrict__ cnt,
                                                 ub16* __restrict__ attno) {
    __shared__ ub16 Ks[32][40];
    __shared__ ub16 Vs[32][40];
    __shared__ float Olds[4][32][33];
    const float rscale = 0.17677669529663688f;   // 1/sqrt(32)

    int bh = blockIdx.x, b = bh >> 3, h = bh & 7;
    int tid = threadIdx.x;
    int w = tid >> 6, lane = tid & 63, hi = lane >> 5, q = lane & 31;
    int qt = blockIdx.y * 4 + w;
    int t = qt * 32 + q;
    int nvalid = cnt[b] + 1;

    bf16x8 bq0 = {}, bq1 = {};
    if (t < TT) {
        const ub16* qp = qkv + ((size_t)(b * TT + t)) * 768 + h * 32 + 8 * hi;
        bq0 = *(const bf16x8*)qp;
        bq1 = *(const bf16x8*)(qp + 16);
    }

    float m = -1e30f, l = 0.0f;
    f32x16 ot = {};
    int nkt = (nvalid + 31) >> 5;

    for (int kt = 0; kt < nkt; ++kt) {
        int k0 = kt << 5;
        __syncthreads();
        {
            int r = tid & 127;
            int krow = r >> 2, c8 = (r & 3) * 8;
            int srow = min(k0 + krow, TT - 1);
            const ub16* sp = qkv + ((size_t)(b * TT + srow)) * 768 +
                             ((tid & 128) ? 512 : 256) + h * 32 + c8;
            bf16x8 kv = *(const bf16x8*)sp;
            if (tid & 128) *(bf16x8*)&Vs[krow][c8] = kv;
            else           *(bf16x8*)&Ks[krow][c8] = kv;
        }
        __syncthreads();

        // S^T tile: rows = keys (crow pattern), cols = queries (lane&31)
        bf16x8 ka0 = *(const bf16x8*)&Ks[q][8 * hi];
        bf16x8 ka1 = *(const bf16x8*)&Ks[q][16 + 8 * hi];
        f32x16 zz = {};
        f32x16 st = __builtin_amdgcn_mfma_f32_32x32x16_bf16(ka0, bq0, zz, 0, 0, 0);
        st = __builtin_amdgcn_mfma_f32_32x32x16_bf16(ka1, bq1, st, 0, 0, 0);

        float pmax = -1e30f;
        bool full = (k0 + 32 <= nvalid);
        #pragma unroll
        for (int r = 0; r < 16; ++r) {
            float s = st[r] * rscale;
            if (!full) {
                int key = k0 + (r & 3) + 8 * (r >> 2) + 4 * hi;
                if (key >= nvalid) s = -1e30f;
            }
            st[r] = s;
            pmax = fmaxf(pmax, s);
        }
        pmax = fmaxf(pmax, __shfl_xor(pmax, 32));
        float mnew = fmaxf(m, pmax);
        float corr = __expf(m - mnew);
        float tsum = 0.0f;
        #pragma unroll
        for (int r = 0; r < 16; ++r) {
            float p = __expf(st[r] - mnew);
            st[r] = p;
            tsum += p;
        }
        tsum += __shfl_xor(tsum, 32);
        l = l * corr + tsum;
        m = mnew;
        #pragma unroll
        for (int r = 0; r < 16; ++r) ot[r] *= corr;

        // pack P -> bf16 B-fragments (keys contiguous-8 per lane via pair swap)
        unsigned wd[8], sx[8];
        #pragma unroll
        for (int i = 0; i < 8; ++i) wd[i] = pk2(st[2 * i], st[2 * i + 1]);
        #pragma unroll
        for (int i = 0; i < 8; ++i) sx[i] = __shfl_xor(wd[i], 32);
        U4B p0, p1;
        if (hi == 0) {
            p0.u[0] = wd[0]; p0.u[1] = wd[1]; p0.u[2] = sx[0]; p0.u[3] = sx[1];
            p1.u[0] = wd[4]; p1.u[1] = wd[5]; p1.u[2] = sx[4]; p1.u[3] = sx[5];
        } else {
            p0.u[0] = sx[2]; p0.u[1] = sx[3]; p0.u[2] = wd[2]; p0.u[3] = wd[3];
            p1.u[0] = sx[6]; p1.u[1] = sx[7]; p1.u[2] = wd[6]; p1.u[3] = wd[7];
        }

        // V^T A-fragments: row = d = lane&31, k = key
        U4B va0, va1;
        #pragma unroll
        for (int j = 0; j < 4; ++j) {
            int kk = 8 * hi + 2 * j;
            va0.u[j] = (unsigned)Vs[kk][q]      | ((unsigned)Vs[kk + 1][q] << 16);
            va1.u[j] = (unsigned)Vs[16 + kk][q] | ((unsigned)Vs[17 + kk][q] << 16);
        }
        ot = __builtin_amdgcn_mfma_f32_32x32x16_bf16(va0.v, p0.v, ot, 0, 0, 0);
        ot = __builtin_amdgcn_mfma_f32_32x32x16_bf16(va1.v, p1.v, ot, 0, 0, 0);
    }

    // write O^T (d = crow, q = lane&31) through LDS transpose, coalesced bf16 out
    float rl = 1.0f / l;
    #pragma unroll
    for (int r = 0; r < 16; ++r) {
        int d = (r & 3) + 8 * (r >> 2) + 4 * hi;
        Olds[w][q][d] = ot[r] * rl;
    }
    __syncthreads();
    int row = lane >> 1, hf = lane & 1;
    int trow = qt * 32 + row;
    if (trow < TT) {
        unsigned wo[8];
        #pragma unroll
        for (int j = 0; j < 8; ++j)
            wo[j] = pk2(Olds[w][row][hf * 16 + 2 * j], Olds[w][row][hf * 16 + 2 * j + 1]);
        ub16* op = attno + ((size_t)(b * TT + trow)) * 256 + h * 32 + hf * 16;
        U4B o0, o1;
        o0.u[0] = wo[0]; o0.u[1] = wo[1]; o0.u[2] = wo[2]; o0.u[3] = wo[3];
        o1.u[0] = wo[4]; o1.u[1] = wo[5]; o1.u[2] = wo[6]; o1.u[3] = wo[7];
        *(bf16x8*)op = o0.v;
        *(bf16x8*)(op + 8) = o1.v;
    }
}

// ---------------- head ----------------
__global__ __launch_bounds__(512) void head_kernel(const float* __restrict__ Y,
                                                   const float* __restrict__ w1,
                                                   const float* __restrict__ b1,
                                                   const float* __restrict__ w2,
                                                   const float* __restrict__ b2,
                                                   float* __restrict__ out) {
    __shared__ float clsr[256];
    __shared__ float t1[512];
    int b = blockIdx.x, tid = threadIdx.x;
    if (tid < 256) clsr[tid] = Y[((size_t)b * TT) * DD + tid];
    __syncthreads();
    float acc = b1[tid];
    const float* w = w1 + (size_t)tid * 256;
    for (int k = 0; k < 256; ++k) acc += clsr[k] * w[k];
    t1[tid] = gelu_f(acc);
    __syncthreads();
    float acc2 = b2[tid];
    const float* wr = w2 + (size_t)tid * 512;
    for (int k = 0; k < 512; ++k) acc2 += t1[k] * wr[k];
    out[(size_t)b * 512 + tid] = acc2;
}

// ---------------- launch ----------------
extern "C" void kernel_launch(void* const* d_in, const int* in_sizes, int n_in,
                              void* d_out, int out_size, void* d_ws, size_t ws_size,
                              hipStream_t stream) {
    (void)in_sizes; (void)n_in; (void)out_size; (void)ws_size;
    const float* expr     = (const float*)d_in[0];
    const float* gene_emb = (const float*)d_in[1];
    const float* ep_w1    = (const float*)d_in[2];
    const float* ep_b1    = (const float*)d_in[3];
    const float* ep_w2    = (const float*)d_in[4];
    const float* ep_b2    = (const float*)d_in[5];
    const float* clsv     = (const float*)d_in[6];
    const float* ln1_s    = (const float*)d_in[7];
    const float* ln1_b    = (const float*)d_in[8];
    const float* qkv_w    = (const float*)d_in[9];
    const float* qkv_b    = (const float*)d_in[10];
    const float* out_w    = (const float*)d_in[11];
    const float* out_b    = (const float*)d_in[12];
    const float* ln2_s    = (const float*)d_in[13];
    const float* ln2_b    = (const float*)d_in[14];
    const float* ff_w1    = (const float*)d_in[15];
    const float* ff_b1    = (const float*)d_in[16];
    const float* ff_w2    = (const float*)d_in[17];
    const float* ff_b2    = (const float*)d_in[18];
    const float* fn_s     = (const float*)d_in[19];
    const float* fn_b     = (const float*)d_in[20];
    const float* pr_w1    = (const float*)d_in[21];
    const float* pr_b1    = (const float*)d_in[22];
    const float* pr_w2    = (const float*)d_in[23];
    const float* pr_b2    = (const float*)d_in[24];
    float* outp = (float*)d_out;

    // workspace layout
    float* x   = (float*)d_ws;                       // BT*256 f32
    float* VAL = x + (size_t)BT * 256;               // 8192*256 f32 (embed out; reused as final LN out)
    ub16* y16   = (ub16*)(VAL + (size_t)8192 * 256);
    ub16* qkv16 = y16 + (size_t)BT * 256;
    ub16* att16 = qkv16 + (size_t)BT * 768;
    ub16* ff116 = att16 + (size_t)BT * 256;
    ub16* H16   = ff116 + (size_t)BT * 1024;
    ub16* wqkv  = H16 + (size_t)8192 * 256;
    ub16* wout  = wqkv + (size_t)LL * 768 * 256;
    ub16* wff1  = wout + (size_t)LL * 256 * 256;
    ub16* wff2  = wff1 + (size_t)LL * 1024 * 256;
    ub16* wep2  = wff2 + (size_t)LL * 256 * 1024;
    int*  idxb  = (int*)(wep2 + (size_t)256 * 256);
    int*  cntb  = idxb + BB * KK;

    // 1) top-K
    topk_kernel<<<BB, 1024, 0, stream>>>(expr, idxb, cntb);

    // 2) weights -> bf16
    cvt_bf16_kernel<<<(LL*768*256 + 255)/256, 256, 0, stream>>>(qkv_w, wqkv, LL*768*256);
    cvt_bf16_kernel<<<(LL*256*256 + 255)/256, 256, 0, stream>>>(out_w, wout, LL*256*256);
    cvt_bf16_kernel<<<(LL*1024*256 + 255)/256, 256, 0, stream>>>(ff_w1, wff1, LL*1024*256);
    cvt_bf16_kernel<<<(LL*256*1024 + 255)/256, 256, 0, stream>>>(ff_w2, wff2, LL*256*1024);
    cvt_bf16_kernel<<<(256*256 + 255)/256, 256, 0, stream>>>(ep_w2, wep2, 256*256);

    // 3) token embeddings
    build_h_kernel<<<(BB * KK * DD) / 256, 256, 0, stream>>>(expr, idxb, cntb, ep_w1, ep_b1, H16);
    gemm_bt16<<<dim3(4, 128), 256, 0, stream>>>(H16, wep2, ep_b2, nullptr, VAL, nullptr,
                                                BB * KK, 256, 256, 0);
    assemble_kernel<<<BT, 256, 0, stream>>>(VAL, gene_emb, clsv, idxb, cntb, x);

    // 4) transformer layers
    for (int i = 0; i < LL; ++i) {
        ln_kernel<<<BT, 256, 0, stream>>>(x, ln1_s + i * DD, ln1_b + i * DD, y16, nullptr);
        gemm_bt16<<<dim3(12, 129), 256, 0, stream>>>(y16, wqkv + (size_t)i * 768 * 256,
                                                     qkv_b + i * 768, nullptr, nullptr, qkv16,
                                                     BT, 768, 256, 0);
        attn_mfma<<<dim3(BB * HH, 17), 256, 0, stream>>>(qkv16, cntb, att16);
        gemm_bt16<<<dim3(4, 129), 256, 0, stream>>>(att16, wout + (size_t)i * 256 * 256,
                                                    out_b + i * 256, x, x, nullptr,
                                                    BT, 256, 256, 0);
        ln_kernel<<<BT, 256, 0, stream>>>(x, ln2_s + i * DD, ln2_b + i * DD, y16, nullptr);
        gemm_bt16<<<dim3(16, 129), 256, 0, stream>>>(y16, wff1 + (size_t)i * 1024 * 256,
                                                     ff_b1 + i * 1024, nullptr, nullptr, ff116,
                                                     BT, 1024, 256, 1);
        gemm_bt16<<<dim3(4, 129), 256, 0, stream>>>(ff116, wff2 + (size_t)i * 256 * 1024,
                                                    ff_b2 + i * 256, x, x, nullptr,
                                                    BT, 256, 1024, 0);
    }

    // 5) final LN + head
    ln_kernel<<<BT, 256, 0, stream>>>(x, fn_s, fn_b, nullptr, VAL);
    head_kernel<<<BB, 512, 0, stream>>>(VAL, pr_w1, pr_b1, pr_w2, pr_b2, outp);
}

// Round 4
// 1279.420 us; speedup vs baseline: 5.4798x; 1.0768x over previous
//
#include <hip/hip_runtime.h>
#include <hip/hip_bf16.h>
#include <math.h>

// Problem constants
#define GG 33538
#define DD 256
#define LL 6
#define HH 8
#define KK 2048
#define BB 4
#define TT 2049          // K+1 tokens
#define BT (BB*TT)       // 8196
#define NT 65            // 32-key tiles per (b,h) (ceil(TT/32) zero-padded)

typedef __bf16 bf16x8 __attribute__((ext_vector_type(8)));
typedef float f32x4 __attribute__((ext_vector_type(4)));
typedef float f32x16 __attribute__((ext_vector_type(16)));
typedef unsigned short ub16;

union BW { __bf16 h; ub16 u; };
__device__ __forceinline__ ub16 f2b(float x) { BW w; w.h = (__bf16)x; return w.u; }
__device__ __forceinline__ unsigned pk2(float a, float b) {
    return (unsigned)f2b(a) | ((unsigned)f2b(b) << 16);
}
union U4B { unsigned u[4]; bf16x8 v; };

__device__ __forceinline__ float gelu_f(float x) {
    return 0.5f * x * (1.0f + erff(x * 0.70710678118654752440f));
}

__device__ __forceinline__ unsigned to_key(float x) {
    unsigned u = __float_as_uint(x);
    return (u & 0x80000000u) ? ~u : (u | 0x80000000u);
}

// ---------------- Top-K (radix select, exact tie handling) ----------------
__device__ int block_scan_excl_1024(int v, int* shw) {
    int lane = threadIdx.x & 63, w = threadIdx.x >> 6;
    int x = v;
    #pragma unroll
    for (int o = 1; o < 64; o <<= 1) {
        int t = __shfl_up(x, o, 64);
        if (lane >= o) x += t;
    }
    if (lane == 63) shw[w] = x;
    __syncthreads();
    if (w == 0) {
        int y = (lane < 16) ? shw[lane] : 0;
        #pragma unroll
        for (int o = 1; o < 16; o <<= 1) {
            int t = __shfl_up(y, o, 64);
            if (lane >= o) y += t;
        }
        if (lane < 16) shw[lane] = y;
    }
    __syncthreads();
    int off = (w == 0) ? 0 : shw[w - 1];
    return off + x - v;   // exclusive prefix
}

__global__ __launch_bounds__(1024) void topk_kernel(const float* __restrict__ expr,
                                                    int* __restrict__ idxout,
                                                    int* __restrict__ cntout) {
    __shared__ unsigned hist[256];
    __shared__ int shw[16];
    __shared__ unsigned sh_prefix;
    __shared__ int sh_want;
    __shared__ int sh_tot;

    int b = blockIdx.x;
    int tid = threadIdx.x;
    const float* row = expr + (size_t)b * GG;

    unsigned prefix = 0;
    int want = KK;
    for (int p = 3; p >= 0; --p) {
        for (int i = tid; i < 256; i += 1024) hist[i] = 0u;
        __syncthreads();
        int shift = p * 8;
        unsigned pmask = (p == 3) ? 0u : (0xFFFFFFFFu << (shift + 8));
        for (int g = tid; g < GG; g += 1024) {
            unsigned key = to_key(row[g]);
            if ((key & pmask) == (prefix & pmask))
                atomicAdd(&hist[(key >> shift) & 255u], 1u);
        }
        __syncthreads();
        if (tid == 0) {
            int cum = 0, bin = 0;
            for (int i = 255; i >= 0; --i) {
                int c = (int)hist[i];
                if (cum + c >= want) { bin = i; break; }
                cum += c;
            }
            sh_prefix = prefix | ((unsigned)bin << shift);
            sh_want = want - cum;
        }
        __syncthreads();
        prefix = sh_prefix;
        want = sh_want;
        __syncthreads();
    }
    unsigned kth = prefix;

    int base_eq = 0, base_out = 0;
    for (int g0 = 0; g0 < GG; g0 += 1024) {
        int g = g0 + tid;
        bool in = (g < GG);
        float e = in ? row[g] : -1.0f;
        unsigned key = in ? to_key(e) : 0u;
        int is_eq = (in && key == kth) ? 1 : 0;

        int eqr = block_scan_excl_1024(is_eq, shw);
        if (tid == 1023) sh_tot = eqr + is_eq;
        __syncthreads();
        int eq_tot = sh_tot;
        int eq_rank = base_eq + eqr;
        base_eq += eq_tot;
        __syncthreads();

        int selected = ((in && key > kth) || (is_eq && eq_rank < want)) ? 1 : 0;
        int act = (selected && e > 0.0f) ? 1 : 0;

        int pos = block_scan_excl_1024(act, shw);
        if (tid == 1023) sh_tot = pos + act;
        __syncthreads();
        int act_tot = sh_tot;
        if (act) idxout[b * KK + base_out + pos] = g;
        base_out += act_tot;
        __syncthreads();
    }
    if (tid == 0) cntout[b] = base_out;
}

// ---------------- weight fp32 -> bf16 ----------------
__global__ __launch_bounds__(256) void cvt_bf16_kernel(const float* __restrict__ s,
                                                       ub16* __restrict__ d, int n) {
    int i = blockIdx.x * 256 + threadIdx.x;
    if (i < n) d[i] = f2b(s[i]);
}

// ---------------- Token embedding ----------------
__global__ __launch_bounds__(256) void build_h_kernel(const float* __restrict__ expr,
                                                      const int* __restrict__ idxb,
                                                      const int* __restrict__ cntb,
                                                      const float* __restrict__ ep_w1,
                                                      const float* __restrict__ ep_b1,
                                                      ub16* __restrict__ H) {
    int i = blockIdx.x * 256 + threadIdx.x;       // < BB*KK*DD
    int r = i >> 8, d = i & 255;
    int b = r >> 11, jj = r & (KK - 1);
    float v = 0.0f;
    if (jj < cntb[b]) {
        int g = idxb[b * KK + jj];
        float e = expr[(size_t)b * GG + g];
        v = gelu_f(e * ep_w1[d] + ep_b1[d]);
    }
    H[i] = f2b(v);
}

__global__ __launch_bounds__(256) void assemble_kernel(const float* __restrict__ VAL,
                                                       const float* __restrict__ gene_emb,
                                                       const float* __restrict__ clsv,
                                                       const int* __restrict__ idxb,
                                                       const int* __restrict__ cntb,
                                                       float* __restrict__ x) {
    int i = blockIdx.x * 256 + threadIdx.x;       // < BT*DD
    int r = i >> 8, d = i & 255;
    int b = r / TT, t = r % TT;
    float v;
    if (t == 0) {
        v = clsv[d];
    } else {
        int jj = t - 1;
        if (jj < cntb[b]) {
            int g = idxb[b * KK + jj];
            v = gene_emb[(size_t)g * DD + d] + VAL[((size_t)b * KK + jj) * DD + d];
        } else {
            v = 0.0f;
        }
    }
    x[i] = v;
}

// ---------------- LayerNorm ----------------
__device__ __forceinline__ float blocksum256(float v, float* sh) {
    #pragma unroll
    for (int o = 1; o < 64; o <<= 1) v += __shfl_xor(v, o, 64);
    int w = threadIdx.x >> 6;
    if ((threadIdx.x & 63) == 0) sh[w] = v;
    __syncthreads();
    float t = sh[0] + sh[1] + sh[2] + sh[3];
    __syncthreads();
    return t;
}

__global__ __launch_bounds__(256) void ln_kernel(const float* __restrict__ X,
                                                 const float* __restrict__ s,
                                                 const float* __restrict__ bsh,
                                                 ub16* __restrict__ Y16,
                                                 float* __restrict__ Yf) {
    __shared__ float sh[4];
    size_t r = blockIdx.x;
    float x = X[r * DD + threadIdx.x];
    float mu = blocksum256(x, sh) * (1.0f / 256.0f);
    float d = x - mu;
    float var = blocksum256(d * d, sh) * (1.0f / 256.0f);
    float y = d * rsqrtf(var + 1e-5f) * s[threadIdx.x] + bsh[threadIdx.x];
    if (Y16) Y16[r * DD + threadIdx.x] = f2b(y);
    else     Yf[r * DD + threadIdx.x] = y;
}

// ---------------- bf16 MFMA NT-GEMM: C = act(A @ W^T + bias) (+R) ----------------
// A: M x K bf16, W: N x K bf16. Tile 64x64, BK=64 (2 sub-buffers), 4 waves.
__global__ __launch_bounds__(256) void gemm_bt16(const ub16* __restrict__ A,
                                                 const ub16* __restrict__ W,
                                                 const float* __restrict__ bias,
                                                 const float* __restrict__ R,
                                                 float* __restrict__ Cf,
                                                 ub16* __restrict__ Ch,
                                                 int M, int N, int K, int gelu_flag) {
    __shared__ ub16 As[2][64][40];
    __shared__ ub16 Ws[2][64][40];
    int tid = threadIdx.x;
    int lane = tid & 63, w = tid >> 6;
    int wr = (w >> 1) * 32, wc = (w & 1) * 32;
    int bm = blockIdx.y * 64, bn = blockIdx.x * 64;
    f32x4 acc[2][2] = {};

    int lrow = tid >> 2, lc8 = (tid & 3) * 8;
    int arow = min(bm + lrow, M - 1);
    const ub16* ap = A + (size_t)arow * K + lc8;
    const ub16* wp = W + (size_t)(bn + lrow) * K + lc8;

    int fr = lane & 15, fc = 8 * (lane >> 4);
    for (int k0 = 0; k0 < K; k0 += 64) {
        bf16x8 av0 = *(const bf16x8*)(ap + k0);
        bf16x8 av1 = *(const bf16x8*)(ap + k0 + 32);
        bf16x8 wv0 = *(const bf16x8*)(wp + k0);
        bf16x8 wv1 = *(const bf16x8*)(wp + k0 + 32);
        *(bf16x8*)&As[0][lrow][lc8] = av0;
        *(bf16x8*)&As[1][lrow][lc8] = av1;
        *(bf16x8*)&Ws[0][lrow][lc8] = wv0;
        *(bf16x8*)&Ws[1][lrow][lc8] = wv1;
        __syncthreads();
        #pragma unroll
        for (int ks = 0; ks < 2; ++ks) {
            bf16x8 a0 = *(const bf16x8*)&As[ks][wr + fr][fc];
            bf16x8 a1 = *(const bf16x8*)&As[ks][wr + 16 + fr][fc];
            bf16x8 b0 = *(const bf16x8*)&Ws[ks][wc + fr][fc];
            bf16x8 b1 = *(const bf16x8*)&Ws[ks][wc + 16 + fr][fc];
            acc[0][0] = __builtin_amdgcn_mfma_f32_16x16x32_bf16(a0, b0, acc[0][0], 0, 0, 0);
            acc[0][1] = __builtin_amdgcn_mfma_f32_16x16x32_bf16(a0, b1, acc[0][1], 0, 0, 0);
            acc[1][0] = __builtin_amdgcn_mfma_f32_16x16x32_bf16(a1, b0, acc[1][0], 0, 0, 0);
            acc[1][1] = __builtin_amdgcn_mfma_f32_16x16x32_bf16(a1, b1, acc[1][1], 0, 0, 0);
        }
        __syncthreads();
    }

    #pragma unroll
    for (int i = 0; i < 2; ++i) {
        #pragma unroll
        for (int j = 0; j < 2; ++j) {
            #pragma unroll
            for (int reg = 0; reg < 4; ++reg) {
                int gm = bm + wr + i * 16 + (lane >> 4) * 4 + reg;
                int gn = bn + wc + j * 16 + (lane & 15);
                if (gm >= M) continue;
                float v = acc[i][j][reg] + bias[gn];
                if (R) v += R[(size_t)gm * N + gn];
                if (gelu_flag) v = gelu_f(v);
                if (Cf) Cf[(size_t)gm * N + gn] = v;
                else    Ch[(size_t)gm * N + gn] = f2b(v);
            }
        }
    }
}

// ---------------- K/V cache prep: dense tiled Kc + transposed Vt ----------------
// Kc[bh][tile][key32][d32], Vt[bh][tile][d32][key32]; zero-padded to NT tiles.
// grid (BB*HH, 33); block 256 handles 64 keys.
__global__ __launch_bounds__(256) void kvprep(const ub16* __restrict__ qkv,
                                              ub16* __restrict__ Kc,
                                              ub16* __restrict__ Vt) {
    __shared__ unsigned vl[32][33];
    int bh = blockIdx.x, b = bh >> 3, h = bh & 7;
    int c = blockIdx.y;                 // 64-key chunk
    int tid = threadIdx.x;
    int krel = tid >> 2;                // 0..63
    int key = c * 64 + krel;
    int d8 = (tid & 3) * 8;
    U4B kv = {}, vv = {};
    if (key < TT) {
        const ub16* p = qkv + ((size_t)(b * TT + key)) * 768 + 256 + h * 32 + d8;
        kv.v = *(const bf16x8*)p;
        vv.v = *(const bf16x8*)(p + 256);
    }
    int kt = c * 2 + (krel >> 5);
    if (kt < NT)
        *(bf16x8*)(Kc + (((size_t)bh * NT + kt) * 32 + (krel & 31)) * 32 + d8) = kv.v;

    // transpose V into LDS dwords: vl[d][keypair] = (even key | odd key<<16)
    unsigned pu[4];
    #pragma unroll
    for (int j = 0; j < 4; ++j) pu[j] = __shfl_xor(vv.u[j], 4);
    if (!(krel & 1)) {
        int kp = krel >> 1;             // 0..31
        #pragma unroll
        for (int j = 0; j < 8; ++j) {
            unsigned mine = (vv.u[j >> 1] >> ((j & 1) * 16)) & 0xffffu;
            unsigned oth  = (pu[j >> 1] >> ((j & 1) * 16)) & 0xffffu;
            vl[d8 + j][kp] = mine | (oth << 16);
        }
    }
    __syncthreads();
    int d = tid >> 3, c8 = tid & 7;     // keys 8*c8..8*c8+7
    U4B o;
    #pragma unroll
    for (int i = 0; i < 4; ++i) o.u[i] = vl[d][c8 * 4 + i];
    int kt2 = c * 2 + (c8 >> 2);
    if (kt2 < NT)
        *(bf16x8*)(Vt + (((size_t)bh * NT + kt2) * 32 + d) * 32 + (c8 & 3) * 8) = o.v;
}

// ---------------- MFMA flash attention v2: no LDS staging, no barriers ----------
// grid (B*H, 17); block 256 = 4 independent waves; wave = one 32-query tile.
__global__ __launch_bounds__(256) void attn_mfma2(const ub16* __restrict__ qkv,
                                                  const ub16* __restrict__ Kc,
                                                  const ub16* __restrict__ Vt,
                                                  const int* __restrict__ cnt,
                                                  ub16* __restrict__ attno) {
    __shared__ float Olds[4][32][33];
    int bh = blockIdx.x, b = bh >> 3, h = bh & 7;
    int tid = threadIdx.x;
    int w = tid >> 6, lane = tid & 63, hi = lane >> 5, q = lane & 31;
    int qt = blockIdx.y * 4 + w;
    if (qt * 32 >= TT) return;          // no barriers anywhere -> safe
    int t = qt * 32 + q;
    int nvalid = cnt[b] + 1;
    int nkt = (nvalid + 31) >> 5;
    int nfull = (nvalid & 31) ? nkt - 1 : nkt;
    const float c1 = 0.17677669529663688f * 1.44269504088896340f; // scale * log2e

    int tc = min(t, TT - 1);
    const ub16* qp = qkv + ((size_t)(b * TT + tc)) * 768 + h * 32 + 8 * hi;
    bf16x8 bq0 = *(const bf16x8*)qp;
    bf16x8 bq1 = *(const bf16x8*)(qp + 16);

    float m = -1e30f, l = 0.0f;
    f32x16 ot = {};

    const ub16* kp = Kc + ((size_t)bh * NT) * 1024 + q * 32 + 8 * hi;
    const ub16* vp = Vt + ((size_t)bh * NT) * 1024 + q * 32 + 8 * hi;
    bf16x8 ka0 = *(const bf16x8*)kp;
    bf16x8 ka1 = *(const bf16x8*)(kp + 16);
    bf16x8 va0 = *(const bf16x8*)vp;
    bf16x8 va1 = *(const bf16x8*)(vp + 16);

    for (int kt = 0; kt < nkt; ++kt) {
        bf16x8 nk0 = ka0, nk1 = ka1, nv0 = va0, nv1 = va1;
        if (kt + 1 < nkt) {             // prefetch next tile
            kp += 1024; vp += 1024;
            nk0 = *(const bf16x8*)kp;
            nk1 = *(const bf16x8*)(kp + 16);
            nv0 = *(const bf16x8*)vp;
            nv1 = *(const bf16x8*)(vp + 16);
        }
        f32x16 zz = {};
        f32x16 st = __builtin_amdgcn_mfma_f32_32x32x16_bf16(ka0, bq0, zz, 0, 0, 0);
        st = __builtin_amdgcn_mfma_f32_32x32x16_bf16(ka1, bq1, st, 0, 0, 0);

        #pragma unroll
        for (int r = 0; r < 16; ++r) st[r] *= c1;
        if (kt >= nfull) {              // only the last (partial) tile
            int k0 = kt << 5;
            #pragma unroll
            for (int r = 0; r < 16; ++r) {
                int key = k0 + (r & 3) + 8 * (r >> 2) + 4 * hi;
                if (key >= nvalid) st[r] = -1e30f;
            }
        }
        float pmax = -1e30f;
        #pragma unroll
        for (int r = 0; r < 16; ++r) pmax = fmaxf(pmax, st[r]);
        pmax = fmaxf(pmax, __shfl_xor(pmax, 32));
        if (!__all(pmax <= m + 8.0f)) { // defer-max: rescale only on real growth
            float mnew = fmaxf(m, pmax);
            float corr = exp2f(m - mnew);
            l *= corr;
            #pragma unroll
            for (int r = 0; r < 16; ++r) ot[r] *= corr;
            m = mnew;
        }
        float tsum = 0.0f;
        #pragma unroll
        for (int r = 0; r < 16; ++r) {
            float p = exp2f(st[r] - m);
            st[r] = p;
            tsum += p;
        }
        tsum += __shfl_xor(tsum, 32);
        l += tsum;

        // pack P -> bf16 B-fragments (keys contiguous-8 per lane via pair swap)
        unsigned wd[8], sx[8];
        #pragma unroll
        for (int i = 0; i < 8; ++i) wd[i] = pk2(st[2 * i], st[2 * i + 1]);
        #pragma unroll
        for (int i = 0; i < 8; ++i) sx[i] = __shfl_xor(wd[i], 32);
        U4B p0, p1;
        if (hi == 0) {
            p0.u[0] = wd[0]; p0.u[1] = wd[1]; p0.u[2] = sx[0]; p0.u[3] = sx[1];
            p1.u[0] = wd[4]; p1.u[1] = wd[5]; p1.u[2] = sx[4]; p1.u[3] = sx[5];
        } else {
            p0.u[0] = sx[2]; p0.u[1] = sx[3]; p0.u[2] = wd[2]; p0.u[3] = wd[3];
            p1.u[0] = sx[6]; p1.u[1] = sx[7]; p1.u[2] = wd[6]; p1.u[3] = wd[7];
        }
        ot = __builtin_amdgcn_mfma_f32_32x32x16_bf16(va0, p0.v, ot, 0, 0, 0);
        ot = __builtin_amdgcn_mfma_f32_32x32x16_bf16(va1, p1.v, ot, 0, 0, 0);

        ka0 = nk0; ka1 = nk1; va0 = nv0; va1 = nv1;
    }

    // O^T -> LDS transpose (wave-private slot, in-wave ordering via waitcnt)
    float rl = 1.0f / l;
    #pragma unroll
    for (int r = 0; r < 16; ++r) {
        int d = (r & 3) + 8 * (r >> 2) + 4 * hi;
        Olds[w][q][d] = ot[r] * rl;
    }
    int row = lane >> 1, hf = lane & 1;
    int trow = qt * 32 + row;
    if (trow < TT) {
        unsigned wo[8];
        #pragma unroll
        for (int j = 0; j < 8; ++j)
            wo[j] = pk2(Olds[w][row][hf * 16 + 2 * j], Olds[w][row][hf * 16 + 2 * j + 1]);
        ub16* op = attno + ((size_t)(b * TT + trow)) * 256 + h * 32 + hf * 16;
        U4B o0, o1;
        o0.u[0] = wo[0]; o0.u[1] = wo[1]; o0.u[2] = wo[2]; o0.u[3] = wo[3];
        o1.u[0] = wo[4]; o1.u[1] = wo[5]; o1.u[2] = wo[6]; o1.u[3] = wo[7];
        *(bf16x8*)op = o0.v;
        *(bf16x8*)(op + 8) = o1.v;
    }
}

// ---------------- head ----------------
__global__ __launch_bounds__(512) void head_kernel(const float* __restrict__ Y,
                                                   const float* __restrict__ w1,
                                                   const float* __restrict__ b1,
                                                   const float* __restrict__ w2,
                                                   const float* __restrict__ b2,
                                                   float* __restrict__ out) {
    __shared__ float clsr[256];
    __shared__ float t1[512];
    int b = blockIdx.x, tid = threadIdx.x;
    if (tid < 256) clsr[tid] = Y[((size_t)b * TT) * DD + tid];
    __syncthreads();
    float acc = b1[tid];
    const float* w = w1 + (size_t)tid * 256;
    for (int k = 0; k < 256; ++k) acc += clsr[k] * w[k];
    t1[tid] = gelu_f(acc);
    __syncthreads();
    float acc2 = b2[tid];
    const float* wr = w2 + (size_t)tid * 512;
    for (int k = 0; k < 512; ++k) acc2 += t1[k] * wr[k];
    out[(size_t)b * 512 + tid] = acc2;
}

// ---------------- launch ----------------
extern "C" void kernel_launch(void* const* d_in, const int* in_sizes, int n_in,
                              void* d_out, int out_size, void* d_ws, size_t ws_size,
                              hipStream_t stream) {
    (void)in_sizes; (void)n_in; (void)out_size; (void)ws_size;
    const float* expr     = (const float*)d_in[0];
    const float* gene_emb = (const float*)d_in[1];
    const float* ep_w1    = (const float*)d_in[2];
    const float* ep_b1    = (const float*)d_in[3];
    const float* ep_w2    = (const float*)d_in[4];
    const float* ep_b2    = (const float*)d_in[5];
    const float* clsv     = (const float*)d_in[6];
    const float* ln1_s    = (const float*)d_in[7];
    const float* ln1_b    = (const float*)d_in[8];
    const float* qkv_w    = (const float*)d_in[9];
    const float* qkv_b    = (const float*)d_in[10];
    const float* out_w    = (const float*)d_in[11];
    const float* out_b    = (const float*)d_in[12];
    const float* ln2_s    = (const float*)d_in[13];
    const float* ln2_b    = (const float*)d_in[14];
    const float* ff_w1    = (const float*)d_in[15];
    const float* ff_b1    = (const float*)d_in[16];
    const float* ff_w2    = (const float*)d_in[17];
    const float* ff_b2    = (const float*)d_in[18];
    const float* fn_s     = (const float*)d_in[19];
    const float* fn_b     = (const float*)d_in[20];
    const float* pr_w1    = (const float*)d_in[21];
    const float* pr_b1    = (const float*)d_in[22];
    const float* pr_w2    = (const float*)d_in[23];
    const float* pr_b2    = (const float*)d_in[24];
    float* outp = (float*)d_out;

    const size_t KVSZ = (size_t)32 * NT * 1024;   // 2,129,920 elems (per cache)

    // workspace layout
    float* x   = (float*)d_ws;                       // BT*256 f32
    float* VAL = x + (size_t)BT * 256;               // 8192*256 f32; reused as Vt + final-LN out
    ub16* y16   = (ub16*)(VAL + (size_t)8192 * 256);
    ub16* qkv16 = y16 + (size_t)BT * 256;
    ub16* att16 = qkv16 + (size_t)BT * 768;
    ub16* ff116 = att16 + (size_t)BT * 256;
    ub16* kc_h  = ff116 + (size_t)BT * 1024;         // max(H16, Kc) region
    ub16* wqkv  = kc_h + KVSZ;
    ub16* wout  = wqkv + (size_t)LL * 768 * 256;
    ub16* wff1  = wout + (size_t)LL * 256 * 256;
    ub16* wff2  = wff1 + (size_t)LL * 1024 * 256;
    ub16* wep2  = wff2 + (size_t)LL * 256 * 1024;
    int*  idxb  = (int*)(wep2 + (size_t)256 * 256);
    int*  cntb  = idxb + BB * KK;
    ub16* H16 = kc_h;          // used only in embed phase
    ub16* Kc  = kc_h;          // used only in layer phase
    ub16* Vt  = (ub16*)VAL;    // used only in layer phase (after assemble)

    // 1) top-K
    topk_kernel<<<BB, 1024, 0, stream>>>(expr, idxb, cntb);

    // 2) weights -> bf16
    cvt_bf16_kernel<<<(LL*768*256 + 255)/256, 256, 0, stream>>>(qkv_w, wqkv, LL*768*256);
    cvt_bf16_kernel<<<(LL*256*256 + 255)/256, 256, 0, stream>>>(out_w, wout, LL*256*256);
    cvt_bf16_kernel<<<(LL*1024*256 + 255)/256, 256, 0, stream>>>(ff_w1, wff1, LL*1024*256);
    cvt_bf16_kernel<<<(LL*256*1024 + 255)/256, 256, 0, stream>>>(ff_w2, wff2, LL*256*1024);
    cvt_bf16_kernel<<<(256*256 + 255)/256, 256, 0, stream>>>(ep_w2, wep2, 256*256);

    // 3) token embeddings
    build_h_kernel<<<(BB * KK * DD) / 256, 256, 0, stream>>>(expr, idxb, cntb, ep_w1, ep_b1, H16);
    gemm_bt16<<<dim3(4, 128), 256, 0, stream>>>(H16, wep2, ep_b2, nullptr, VAL, nullptr,
                                                BB * KK, 256, 256, 0);
    assemble_kernel<<<BT, 256, 0, stream>>>(VAL, gene_emb, clsv, idxb, cntb, x);

    // 4) transformer layers
    for (int i = 0; i < LL; ++i) {
        ln_kernel<<<BT, 256, 0, stream>>>(x, ln1_s + i * DD, ln1_b + i * DD, y16, nullptr);
        gemm_bt16<<<dim3(12, 129), 256, 0, stream>>>(y16, wqkv + (size_t)i * 768 * 256,
                                                     qkv_b + i * 768, nullptr, nullptr, qkv16,
                                                     BT, 768, 256, 0);
        kvprep<<<dim3(BB * HH, 33), 256, 0, stream>>>(qkv16, Kc, Vt);
        attn_mfma2<<<dim3(BB * HH, 17), 256, 0, stream>>>(qkv16, Kc, Vt, cntb, att16);
        gemm_bt16<<<dim3(4, 129), 256, 0, stream>>>(att16, wout + (size_t)i * 256 * 256,
                                                    out_b + i * 256, x, x, nullptr,
                                                    BT, 256, 256, 0);
        ln_kernel<<<BT, 256, 0, stream>>>(x, ln2_s + i * DD, ln2_b + i * DD, y16, nullptr);
        gemm_bt16<<<dim3(16, 129), 256, 0, stream>>>(y16, wff1 + (size_t)i * 1024 * 256,
                                                     ff_b1 + i * 1024, nullptr, nullptr, ff116,
                                                     BT, 1024, 256, 1);
        gemm_bt16<<<dim3(4, 129), 256, 0, stream>>>(ff116, wff2 + (size_t)i * 256 * 1024,
                                                    ff_b2 + i * 256, x, x, nullptr,
                                                    BT, 256, 1024, 0);
    }

    // 5) final LN + head
    ln_kernel<<<BT, 256, 0, stream>>>(x, fn_s, fn_b, nullptr, VAL);
    head_kernel<<<BB, 512, 0, stream>>>(VAL, pr_w1, pr_b1, pr_w2, pr_b2, outp);
}